// Round 10
// baseline (115.032 us; speedup 1.0000x reference)
//
#include <hip/hip_runtime.h>
#include <stdint.h>

#define BB 256
#define CC 64
#define CVV 4
#define LL 2048
#define NR (CC + CVV)   // 68 rows per block (= per batch)

// LDS-only barrier: orders ds ops across waves WITHOUT draining vmcnt
// (__syncthreads would emit s_waitcnt vmcnt(0) and stall the load stream).
#define SBAR_LDS() do { \
    asm volatile("s_waitcnt lgkmcnt(0)" ::: "memory"); \
    __builtin_amdgcn_s_barrier(); \
    __builtin_amdgcn_sched_barrier(0); \
  } while (0)

__device__ __forceinline__ void ce_desc(unsigned long long* key, int i, int j,
                                        bool descBlk) {
  unsigned long long a = key[i], c = key[j];
  bool sw = descBlk ? (a < c) : (a > c);
  if (sw) { key[i] = c; key[j] = a; }
}

// ---------------------------------------------------------------------------
// One block per batch (256 blocks = 1/CU, 512 threads = 8 waves).
// Phase 1: stable descending argsort of rand_f (bitonic, composite keys
//   ord(rand_f)<<32 | (L-1-idx), wave-segment optimized, LDS-only barriers).
//   Perm for this thread's 4 output slots -> int4 register; mask_t written
//   directly. Mask layout detect via uniform scalar loads.
// Phase 2: REGISTER-STAGED gather (no global_load_lds - its LDS-DMA queue
//   appears to cap effective prefetch depth; plain VMEM loads sustain deep
//   queues). 8-deep named-reg ring r[0..7] (static idx via full unroll),
//   4-slot LDS ring (32 KB), TWO rows per raw barrier (34 barriers).
//   Per pair pp: ds_write rows {2pp,2pp+1} from regs -> SBAR -> reissue
//   loads for rows {2pp+8,2pp+9} into the just-freed regs -> gather+store.
//   Compiler inserts precise counted vmcnt before each ds_write (tracks the
//   per-register load), and lgkmcnt before stores. Ring safety: pair pp
//   writes slots {0,1} or {2,3}; those were last read at pair pp-2, which
//   all waves finished before barrier(pp-1) < write time. 
// ---------------------------------------------------------------------------
__global__ __launch_bounds__(512) void trimmer_kernel(
    const float* __restrict__ x, const float* __restrict__ v,
    const void* __restrict__ mask, const float* __restrict__ rnd,
    float* __restrict__ xo, float* __restrict__ vo, float* __restrict__ mo) {
  __shared__ union {
    unsigned long long key[LL];   // 16 KB = ring slots 0-1
    float ring[4][LL];            // 4 x 8 KB = 32 KB
  } sh;
  __shared__ int wcnt[8];

  const int b = blockIdx.x;
  const int tid = threadIdx.x;
  const int w = tid >> 6;
  const int lane = tid & 63;
  const unsigned* m32 = (const unsigned*)mask;

  // --- scalar-load layout detect (uniform address -> s_load) ---
  unsigned acc = 0;
#pragma unroll
  for (int j = 0; j < 16; ++j) acc |= m32[(size_t)b * 512 + j];
  const bool is_byte = (acc != 0u) && (acc != 1u) && (acc != 0x3F800000u);

  // --- register loads of rand + mask for key build ---
  float rv[4]; unsigned mw[4];
#pragma unroll
  for (int k = 0; k < 4; ++k) {
    const int l = tid + 512 * k;
    rv[k] = rnd[(size_t)b * LL + l];
    mw[k] = is_byte ? m32[(size_t)b * 512 + (l >> 2)]
                    : m32[(size_t)b * LL + l];
  }

  const float* const xs = x + (size_t)b * CC * LL;
  const float* const vs = v + (size_t)b * CVV * LL;
  float* const xd = xo + (size_t)b * CC * LL;
  float* const vd = vo + (size_t)b * CVV * LL;

#define SRCROW(rr) ((rr) < CC ? xs + (size_t)(rr) * LL \
                              : vs + (size_t)((rr) - CC) * LL)
#define DSTROW(rr) ((rr) < CC ? xd + (size_t)(rr) * LL \
                              : vd + (size_t)((rr) - CC) * LL)

  // --- prefetch rows 0..7 into the register ring (flows under the sort) ---
  float4 r[8];
#pragma unroll
  for (int k = 0; k < 8; ++k)
    r[k] = ((const float4*)SRCROW(k))[tid];
  asm volatile("" ::: "memory");  // keep issues above the sort barriers

  // --- build composite keys ---
  const int sh8 = 8 * (tid & 3);
  int local = 0;
#pragma unroll
  for (int k = 0; k < 4; ++k) {
    const int l = tid + 512 * k;
    const bool m = is_byte ? (((mw[k] >> sh8) & 0xFFu) != 0u) : (mw[k] != 0u);
    float rf = m ? -1.0f : rv[k];
    unsigned u = __float_as_uint(rf);
    u = (u & 0x80000000u) ? ~u : (u | 0x80000000u);  // order-preserving map
    sh.key[l] = ((unsigned long long)u << 32) | (unsigned)(LL - 1 - l);
    local += m ? 1 : 0;
  }
#pragma unroll
  for (int off = 32; off > 0; off >>= 1) local += __shfl_down(local, off, 64);
  if (lane == 0) wcnt[w] = local;
  SBAR_LDS();

  // --- bitonic sort, descending; wave w owns key[w*256 .. w*256+255] ---
  for (int size = 2; size <= 256; size <<= 1) {
    for (int stride = size >> 1; stride > 0; stride >>= 1) {
#pragma unroll
      for (int pp = 0; pp < 2; ++pp) {
        int p = w * 128 + pp * 64 + lane;
        int i = ((p & ~(stride - 1)) << 1) | (p & (stride - 1));
        ce_desc(sh.key, i, i + stride, (i & size) == 0);
      }
      __builtin_amdgcn_wave_barrier();
    }
  }
  SBAR_LDS();
  for (int size = 512; size <= 2048; size <<= 1) {
    for (int stride = size >> 1; stride >= 256; stride >>= 1) {
      for (int t = tid; t < LL / 2; t += 512) {
        int i = ((t & ~(stride - 1)) << 1) | (t & (stride - 1));
        ce_desc(sh.key, i, i + stride, (i & size) == 0);
      }
      SBAR_LDS();
    }
    for (int stride = 128; stride > 0; stride >>= 1) {
#pragma unroll
      for (int pp = 0; pp < 2; ++pp) {
        int p = w * 128 + pp * 64 + lane;
        int i = ((p & ~(stride - 1)) << 1) | (p & (stride - 1));
        ce_desc(sh.key, i, i + stride, (i & size) == 0);
      }
      __builtin_amdgcn_wave_barrier();
    }
    SBAR_LDS();
  }

  // --- extract perm into registers; write mask_t ---
  const int cnt = wcnt[0] + wcnt[1] + wcnt[2] + wcnt[3] +
                  wcnt[4] + wcnt[5] + wcnt[6] + wcnt[7];
  const int maxlen = cnt > 1 ? cnt : 1;              // jnp.maximum(count, 1)
  const unsigned ordNeg1 = ~__float_as_uint(-1.0f);  // ord(-1.0)
  int sv[4]; float mf[4];
#pragma unroll
  for (int k = 0; k < 4; ++k) {
    const int j = tid * 4 + k;
    unsigned long long k2 = sh.key[j];
    int idx = (LL - 1) - (int)(unsigned)(k2 & 0xFFFFFFFFull);
    bool masked = ((unsigned)(k2 >> 32)) == ordNeg1;
    bool keep = j < maxlen;
    sv[k] = idx | (keep ? (1 << 12) : 0);
    mf[k] = (keep && masked) ? 1.0f : 0.0f;
  }
  const int4 s = make_int4(sv[0], sv[1], sv[2], sv[3]);
  ((float4*)(mo + (size_t)b * LL))[tid] =
      make_float4(mf[0], mf[1], mf[2], mf[3]);
  SBAR_LDS();  // all key[] reads done before ring slots 0,1 get written

  // one pair of rows: ds_write 2 rows from regs, barrier, reissue, gather 2
#define GATHER1(buf, dst) do { \
    float4 o; \
    o.x = (s.x & (1 << 12)) ? (buf)[s.x & 0x7FF] : 0.0f; \
    o.y = (s.y & (1 << 12)) ? (buf)[s.y & 0x7FF] : 0.0f; \
    o.z = (s.z & (1 << 12)) ? (buf)[s.z & 0x7FF] : 0.0f; \
    o.w = (s.w & (1 << 12)) ? (buf)[s.w & 0x7FF] : 0.0f; \
    ((float4*)(dst))[tid] = o; \
  } while (0)

#define PAIR(pp, k) do { \
    const int r0 = 2 * (pp), r1 = r0 + 1; \
    const int q0 = 2 * (k) & 3, q1 = (2 * (k) + 1) & 3; \
    ((float4*)&sh.ring[q0][0])[tid] = r[2 * (k)]; \
    ((float4*)&sh.ring[q1][0])[tid] = r[2 * (k) + 1]; \
    SBAR_LDS(); \
    if (r0 + 8 < NR) r[2 * (k)]     = ((const float4*)SRCROW(r0 + 8))[tid]; \
    if (r1 + 8 < NR) r[2 * (k) + 1] = ((const float4*)SRCROW(r1 + 8))[tid]; \
    GATHER1(&sh.ring[q0][0], DSTROW(r0)); \
    GATHER1(&sh.ring[q1][0], DSTROW(r1)); \
  } while (0)

  // 34 pairs: 8 macro-iters x 4 (static reg indices) + 2 epilogue pairs
#pragma unroll 1
  for (int mi = 0; mi < 8; ++mi) {
    const int base = mi * 4;
    PAIR(base + 0, 0);
    PAIR(base + 1, 1);
    PAIR(base + 2, 2);
    PAIR(base + 3, 3);
  }
  PAIR(32, 0);  // rows 64,65 (regs r[0],r[1], loaded at pair 28)
  PAIR(33, 1);  // rows 66,67 (regs r[2],r[3], loaded at pair 29)
#undef PAIR
#undef GATHER1
#undef SRCROW
#undef DSTROW
}

extern "C" void kernel_launch(void* const* d_in, const int* in_sizes, int n_in,
                              void* d_out, int out_size, void* d_ws, size_t ws_size,
                              hipStream_t stream) {
  const float* x    = (const float*)d_in[0];
  const float* v    = (const float*)d_in[1];
  const void*  mask = d_in[2];
  const float* rnd  = (const float*)d_in[3];

  float* xo = (float*)d_out;                  // B*C*L
  float* vo = xo + (size_t)BB * CC * LL;      // B*CV*L
  float* mo = vo + (size_t)BB * CVV * LL;     // B*1*L

  trimmer_kernel<<<BB, 512, 0, stream>>>(x, v, mask, rnd, xo, vo, mo);
}

// Round 11
// 66.603 us; speedup vs baseline: 1.7271x; 1.7271x over previous
//
#include <hip/hip_runtime.h>
#include <stdint.h>

#define BB 256
#define CC 64
#define CVV 4
#define LL 2048
#define NR (CC + CVV)   // 68 rows per block (= per batch)

// LDS-only barrier: orders ds ops across waves WITHOUT draining vmcnt
// (__syncthreads would emit s_waitcnt vmcnt(0) and stall the load stream).
#define SBAR_LDS() do { \
    asm volatile("s_waitcnt lgkmcnt(0)" ::: "memory"); \
    __builtin_amdgcn_s_barrier(); \
    __builtin_amdgcn_sched_barrier(0); \
  } while (0)

__device__ __forceinline__ void ce_desc(unsigned long long* key, int i, int j,
                                        bool descBlk) {
  unsigned long long a = key[i], c = key[j];
  bool sw = descBlk ? (a < c) : (a > c);
  if (sw) { key[i] = c; key[j] = a; }
}

// ---------------------------------------------------------------------------
// One block per batch (256 blocks = 1/CU, 512 threads = 8 waves).
// Phase 1: stable descending argsort of rand_f (bitonic on composite keys
//   ord(rand_f)<<32 | (L-1-idx), wave-segment optimized, LDS-only barriers).
//   Perm for this thread's 4 output slots -> int4 register; mask_t written
//   directly. Mask layout detect via uniform scalar loads.
// Phase 2: register-staged gather with EIGHT NAMED float4 registers a0..a7
//   (R10's float4 r[8] array was demoted to scratch: VGPR=24, WRITE_SIZE
//   doubled. Named scalars via macro substitution cannot alloca.)
//   4-slot LDS ring (32 KB), TWO rows per raw barrier (34 barriers), no
//   vmcnt drain anywhere in the loop — the compiler tracks each named
//   register's load precisely and waits exactly when the ds_write needs it.
//   Pair pp: ds_write rows {2pp,2pp+1} from regs -> SBAR -> reload regs
//   with rows {2pp+8,2pp+9} -> gather+store rows {2pp,2pp+1}.
//   Ring safety: pair pp writes slots {0,1} or {2,3}, last read at pair
//   pp-2; every wave's reads finished before it crossed barrier pp-1.
// ---------------------------------------------------------------------------
__global__ __launch_bounds__(512) void trimmer_kernel(
    const float* __restrict__ x, const float* __restrict__ v,
    const void* __restrict__ mask, const float* __restrict__ rnd,
    float* __restrict__ xo, float* __restrict__ vo, float* __restrict__ mo) {
  __shared__ union {
    unsigned long long key[LL];   // 16 KB = ring slots 0-1
    float ring[4][LL];            // 4 x 8 KB = 32 KB
  } sh;
  __shared__ int wcnt[8];

  const int b = blockIdx.x;
  const int tid = threadIdx.x;
  const int w = tid >> 6;
  const int lane = tid & 63;
  const unsigned* m32 = (const unsigned*)mask;

  // --- scalar-load layout detect (uniform address -> s_load) ---
  unsigned acc = 0;
#pragma unroll
  for (int j = 0; j < 16; ++j) acc |= m32[(size_t)b * 512 + j];
  const bool is_byte = (acc != 0u) && (acc != 1u) && (acc != 0x3F800000u);

  // --- register loads of rand + mask for key build ---
  float rv[4]; unsigned mw[4];
#pragma unroll
  for (int k = 0; k < 4; ++k) {
    const int l = tid + 512 * k;
    rv[k] = rnd[(size_t)b * LL + l];
    mw[k] = is_byte ? m32[(size_t)b * 512 + (l >> 2)]
                    : m32[(size_t)b * LL + l];
  }

  const float* const xs = x + (size_t)b * CC * LL;
  const float* const vs = v + (size_t)b * CVV * LL;
  float* const xd = xo + (size_t)b * CC * LL;
  float* const vd = vo + (size_t)b * CVV * LL;

#define SRCROW(rr) ((rr) < CC ? xs + (size_t)(rr) * LL \
                              : vs + (size_t)((rr) - CC) * LL)
#define DSTROW(rr) ((rr) < CC ? xd + (size_t)(rr) * LL \
                              : vd + (size_t)((rr) - CC) * LL)

  // --- prefetch rows 0..7 into NAMED registers (flows under the sort) ---
  float4 a0 = ((const float4*)SRCROW(0))[tid];
  float4 a1 = ((const float4*)SRCROW(1))[tid];
  float4 a2 = ((const float4*)SRCROW(2))[tid];
  float4 a3 = ((const float4*)SRCROW(3))[tid];
  float4 a4 = ((const float4*)SRCROW(4))[tid];
  float4 a5 = ((const float4*)SRCROW(5))[tid];
  float4 a6 = ((const float4*)SRCROW(6))[tid];
  float4 a7 = ((const float4*)SRCROW(7))[tid];

  // --- build composite keys ---
  const int sh8 = 8 * (tid & 3);
  int local = 0;
#pragma unroll
  for (int k = 0; k < 4; ++k) {
    const int l = tid + 512 * k;
    const bool m = is_byte ? (((mw[k] >> sh8) & 0xFFu) != 0u) : (mw[k] != 0u);
    float rf = m ? -1.0f : rv[k];
    unsigned u = __float_as_uint(rf);
    u = (u & 0x80000000u) ? ~u : (u | 0x80000000u);  // order-preserving map
    sh.key[l] = ((unsigned long long)u << 32) | (unsigned)(LL - 1 - l);
    local += m ? 1 : 0;
  }
#pragma unroll
  for (int off = 32; off > 0; off >>= 1) local += __shfl_down(local, off, 64);
  if (lane == 0) wcnt[w] = local;
  SBAR_LDS();

  // --- bitonic sort, descending; wave w owns key[w*256 .. w*256+255] ---
  for (int size = 2; size <= 256; size <<= 1) {
    for (int stride = size >> 1; stride > 0; stride >>= 1) {
#pragma unroll
      for (int pp = 0; pp < 2; ++pp) {
        int p = w * 128 + pp * 64 + lane;
        int i = ((p & ~(stride - 1)) << 1) | (p & (stride - 1));
        ce_desc(sh.key, i, i + stride, (i & size) == 0);
      }
      __builtin_amdgcn_wave_barrier();
    }
  }
  SBAR_LDS();
  for (int size = 512; size <= 2048; size <<= 1) {
    for (int stride = size >> 1; stride >= 256; stride >>= 1) {
      for (int t = tid; t < LL / 2; t += 512) {
        int i = ((t & ~(stride - 1)) << 1) | (t & (stride - 1));
        ce_desc(sh.key, i, i + stride, (i & size) == 0);
      }
      SBAR_LDS();
    }
    for (int stride = 128; stride > 0; stride >>= 1) {
#pragma unroll
      for (int pp = 0; pp < 2; ++pp) {
        int p = w * 128 + pp * 64 + lane;
        int i = ((p & ~(stride - 1)) << 1) | (p & (stride - 1));
        ce_desc(sh.key, i, i + stride, (i & size) == 0);
      }
      __builtin_amdgcn_wave_barrier();
    }
    SBAR_LDS();
  }

  // --- extract perm into registers; write mask_t ---
  const int cnt = wcnt[0] + wcnt[1] + wcnt[2] + wcnt[3] +
                  wcnt[4] + wcnt[5] + wcnt[6] + wcnt[7];
  const int maxlen = cnt > 1 ? cnt : 1;              // jnp.maximum(count, 1)
  const unsigned ordNeg1 = ~__float_as_uint(-1.0f);  // ord(-1.0)
  int sv[4]; float mf[4];
#pragma unroll
  for (int k = 0; k < 4; ++k) {
    const int j = tid * 4 + k;
    unsigned long long k2 = sh.key[j];
    int idx = (LL - 1) - (int)(unsigned)(k2 & 0xFFFFFFFFull);
    bool masked = ((unsigned)(k2 >> 32)) == ordNeg1;
    bool keep = j < maxlen;
    sv[k] = idx | (keep ? (1 << 12) : 0);
    mf[k] = (keep && masked) ? 1.0f : 0.0f;
  }
  const int4 s = make_int4(sv[0], sv[1], sv[2], sv[3]);
  ((float4*)(mo + (size_t)b * LL))[tid] =
      make_float4(mf[0], mf[1], mf[2], mf[3]);
  SBAR_LDS();  // all key[] reads done before ring slots 0,1 get written

#define GATHER1(buf, dst) do { \
    float4 o; \
    o.x = (s.x & (1 << 12)) ? (buf)[s.x & 0x7FF] : 0.0f; \
    o.y = (s.y & (1 << 12)) ? (buf)[s.y & 0x7FF] : 0.0f; \
    o.z = (s.z & (1 << 12)) ? (buf)[s.z & 0x7FF] : 0.0f; \
    o.w = (s.w & (1 << 12)) ? (buf)[s.w & 0x7FF] : 0.0f; \
    ((float4*)(dst))[tid] = o; \
  } while (0)

  // One pair of rows: ds_write 2 rows from named regs, barrier, reload the
  // same named regs with rows +8, gather+store the 2 rows.
#define PAIR(pp, A, B) do { \
    const int r0 = 2 * (pp), r1 = r0 + 1; \
    const int q0 = (2 * (pp)) & 3, q1 = (2 * (pp) + 1) & 3; \
    ((float4*)&sh.ring[q0][0])[tid] = A; \
    ((float4*)&sh.ring[q1][0])[tid] = B; \
    SBAR_LDS(); \
    if (r0 + 8 < NR) A = ((const float4*)SRCROW(r0 + 8))[tid]; \
    if (r1 + 8 < NR) B = ((const float4*)SRCROW(r1 + 8))[tid]; \
    GATHER1(&sh.ring[q0][0], DSTROW(r0)); \
    GATHER1(&sh.ring[q1][0], DSTROW(r1)); \
  } while (0)

  // 34 pairs: 8 macro-iters x 4 pairs (rows 0..63) + 2 epilogue pairs
#pragma unroll 1
  for (int mi = 0; mi < 8; ++mi) {
    PAIR(mi * 4 + 0, a0, a1);
    PAIR(mi * 4 + 1, a2, a3);
    PAIR(mi * 4 + 2, a4, a5);
    PAIR(mi * 4 + 3, a6, a7);
  }
  PAIR(32, a0, a1);  // rows 64,65 (loaded at pair 28)
  PAIR(33, a2, a3);  // rows 66,67 (loaded at pair 29)
#undef PAIR
#undef GATHER1
#undef SRCROW
#undef DSTROW
}

extern "C" void kernel_launch(void* const* d_in, const int* in_sizes, int n_in,
                              void* d_out, int out_size, void* d_ws, size_t ws_size,
                              hipStream_t stream) {
  const float* x    = (const float*)d_in[0];
  const float* v    = (const float*)d_in[1];
  const void*  mask = d_in[2];
  const float* rnd  = (const float*)d_in[3];

  float* xo = (float*)d_out;                  // B*C*L
  float* vo = xo + (size_t)BB * CC * LL;      // B*CV*L
  float* mo = vo + (size_t)BB * CVV * LL;     // B*1*L

  trimmer_kernel<<<BB, 512, 0, stream>>>(x, v, mask, rnd, xo, vo, mo);
}